// Round 7
// baseline (125.654 us; speedup 1.0000x reference)
//
#include <hip/hip_runtime.h>

// MFVIConstituency: q[b,i,j] = s_con[b,i,j] + sum_k sig(q)[b,j,k] * s_bin[b,i,j,k] * (i!=k)*(j!=k)*mask[b,i,j]
// MAX_ITER=3, output sigmoid(q). Memory-bound; floor = one HBM read of s_bin (227 MB ~ 36us).
//
// R7: batches are independent (q[b] depends only on sig[b]). Process in chunks
// of 2 batches x 3 iterations (12 dispatches). Iter1 of a chunk reads 56.6 MB
// fp32 s_bin (non-temporal) and writes a 28.3 MB masked fp16 copy into a REUSED
// ws region (11% of L3, overwritten in place each chunk). Iters 2-3 re-read the
// copy within ~10us of writing -> should be Infinity-Cache-resident.
// Experiment: tests whether L3 retains a small working set across dispatches
// (R4/R6 showed zero retention at 113-227 MB scale).

#define S_DIM 192
#define SS (S_DIM * S_DIM)
#define B_DIM 8
#define NROWS (B_DIM * SS)      // 294912 outputs
#define CHUNK_B 2               // batches per chunk
#define CHUNK_ROWS (CHUNK_B * SS)

typedef float floatx4 __attribute__((ext_vector_type(4)));
struct alignas(8) half4 { _Float16 x, y, z, w; };

__device__ __forceinline__ float sigmoidf(float x) {
    return 1.0f / (1.0f + __expf(-x));
}

// chunk iter 1: fp32 s_bin (NT stream), fold k-mask, emit fp16 copy + sig(q1)
__global__ __launch_bounds__(256) void fvi_first_kernel(const float* __restrict__ s_con,
                                                        const float* __restrict__ s_bin,
                                                        const int* __restrict__ mask,
                                                        half4* __restrict__ sbh,
                                                        float* __restrict__ sig_out,
                                                        int row_base) {
    const int wave = threadIdx.x >> 6;
    const int lane = threadIdx.x & 63;
    const int grp  = lane >> 4;
    const int sub  = lane & 15;
    const int lrow = (blockIdx.x * 4 + wave) * 4 + grp;   // row within chunk
    const int row  = row_base + lrow;

    const int b   = row / SS;
    const int rem = row - b * SS;
    const int i   = rem / S_DIM;
    const int j   = rem - i * S_DIM;

    const floatx4* __restrict__ srow = reinterpret_cast<const floatx4*>(s_bin + (size_t)row * S_DIM);
    const float4*  __restrict__ grow = reinterpret_cast<const float4*>(s_con + (size_t)(b * SS + j * S_DIM));
    half4* __restrict__ hrow = sbh + (size_t)lrow * (S_DIM / 4);   // chunk-local, reused region

    float dot = 0.0f;
    #pragma unroll
    for (int c = 0; c < 3; ++c) {
        const int f4 = sub + (c << 4);               // 0..47
        floatx4 sv = __builtin_nontemporal_load(srow + f4);
        float4  gv = grow[f4];
        const int k0 = f4 << 2;
        const float m0 = (k0 + 0 != i && k0 + 0 != j) ? sv.x : 0.0f;
        const float m1 = (k0 + 1 != i && k0 + 1 != j) ? sv.y : 0.0f;
        const float m2 = (k0 + 2 != i && k0 + 2 != j) ? sv.z : 0.0f;
        const float m3 = (k0 + 3 != i && k0 + 3 != j) ? sv.w : 0.0f;
        dot += m0 * sigmoidf(gv.x) + m1 * sigmoidf(gv.y)
             + m2 * sigmoidf(gv.z) + m3 * sigmoidf(gv.w);
        half4 hv;
        hv.x = (_Float16)m0; hv.y = (_Float16)m1;
        hv.z = (_Float16)m2; hv.w = (_Float16)m3;
        hrow[f4] = hv;
    }

    dot += __shfl_xor(dot, 1, 64);
    dot += __shfl_xor(dot, 2, 64);
    dot += __shfl_xor(dot, 4, 64);
    dot += __shfl_xor(dot, 8, 64);

    if (sub == 0) {
        float q = s_con[row] + (mask[row] ? dot : 0.0f);
        sig_out[row] = sigmoidf(q);
    }
}

// chunk iters 2..3: read masked fp16 copy (hopefully L3-resident)
__global__ __launch_bounds__(256) void fvi_later_kernel(const float* __restrict__ s_con,
                                                        const half4* __restrict__ sbh,
                                                        const int* __restrict__ mask,
                                                        const float* __restrict__ sig_in,
                                                        float* __restrict__ sig_out,
                                                        int row_base) {
    const int wave = threadIdx.x >> 6;
    const int lane = threadIdx.x & 63;
    const int grp  = lane >> 4;
    const int sub  = lane & 15;
    const int lrow = (blockIdx.x * 4 + wave) * 4 + grp;
    const int row  = row_base + lrow;

    const int b   = row / SS;
    const int rem = row - b * SS;
    const int j   = rem - (rem / S_DIM) * S_DIM;

    const half4*  __restrict__ hrow = sbh + (size_t)lrow * (S_DIM / 4);
    const float4* __restrict__ grow = reinterpret_cast<const float4*>(sig_in + (size_t)(b * SS + j * S_DIM));

    float dot = 0.0f;
    #pragma unroll
    for (int c = 0; c < 3; ++c) {
        const int f4 = sub + (c << 4);
        half4  hv = hrow[f4];
        float4 gv = grow[f4];
        dot += (float)hv.x * gv.x + (float)hv.y * gv.y
             + (float)hv.z * gv.z + (float)hv.w * gv.w;
    }

    dot += __shfl_xor(dot, 1, 64);
    dot += __shfl_xor(dot, 2, 64);
    dot += __shfl_xor(dot, 4, 64);
    dot += __shfl_xor(dot, 8, 64);

    if (sub == 0) {
        float q = s_con[row] + (mask[row] ? dot : 0.0f);
        sig_out[row] = sigmoidf(q);
    }
}

extern "C" void kernel_launch(void* const* d_in, const int* in_sizes, int n_in,
                              void* d_out, int out_size, void* d_ws, size_t ws_size,
                              hipStream_t stream) {
    const float* s_con = (const float*)d_in[0];
    const float* s_bin = (const float*)d_in[1];
    const int*   mask  = (const int*)d_in[2];   // harness widens bool -> int32
    float* out  = (float*)d_out;
    float* sigA = (float*)d_ws;
    float* sigB = sigA + NROWS;
    half4* sbh  = reinterpret_cast<half4*>(sigB + NROWS);  // 28.3 MB reused fp16 region

    const dim3 grid(CHUNK_ROWS / 16);   // 4608 blocks per dispatch

    for (int c = 0; c < B_DIM / CHUNK_B; ++c) {
        const int row_base = c * CHUNK_ROWS;
        fvi_first_kernel<<<grid, 256, 0, stream>>>(s_con, s_bin, mask, sbh, sigA, row_base);
        fvi_later_kernel<<<grid, 256, 0, stream>>>(s_con, sbh, mask, sigA, sigB, row_base);
        fvi_later_kernel<<<grid, 256, 0, stream>>>(s_con, sbh, mask, sigB, out, row_base);
    }
}

// Round 9
// 104.319 us; speedup vs baseline: 1.2045x; 1.2045x over previous
//
#include <hip/hip_runtime.h>
#include <hip/hip_cooperative_groups.h>

// MFVIConstituency: q[b,i,j] = s_con[b,i,j] + sum_k sig(q)[b,j,k] * s_bin[b,i,j,k] * (i!=k)*(j!=k)*mask[b,i,j]
// MAX_ITER=3, output sigmoid(q).
//
// R9: cooperative kernel, block = (batch, j). Its 192 s_bin rows are loaded
// ONCE (fp32 NT, k-mask folded) into 72 VGPRs/thread as fp16, reused across
// all 3 iterations with grid.sync() between them. Per iteration a block reads
// only sig[b,j,:] (768 B via LDS). HBM traffic 566 -> ~230 MB (irreducible).
// R8 failed because the cooperative launch was rejected silently -> this round
// queries occupancy, checks return codes, and cascades CB4 -> CB2 -> R6 path.

#define S_DIM 192
#define SS (S_DIM * S_DIM)
#define B_DIM 8
#define NROWS (B_DIM * SS)
#define NPASS (S_DIM / 16)              // 12: 4 waves x 4 rows per pass

typedef float    floatx4 __attribute__((ext_vector_type(4)));
typedef _Float16 halfx4  __attribute__((ext_vector_type(4)));
struct alignas(8) half4s { _Float16 x, y, z, w; };

__device__ __forceinline__ float sigmoidf(float x) {
    return 1.0f / (1.0f + __expf(-x));
}

// ---------------- cooperative path ----------------
template <int CB>
__global__ __launch_bounds__(256, (CB >= 4 ? 3 : 2))
void fvi_coop_kernel(const float* __restrict__ s_con,
                     const float* __restrict__ s_bin,
                     const int* __restrict__ mask,
                     float* __restrict__ sigA,
                     float* __restrict__ sigB,
                     float* __restrict__ out) {
    cooperative_groups::grid_group grid = cooperative_groups::this_grid();
    __shared__ __align__(16) float sig_row[S_DIM];

    const int tid  = threadIdx.x;
    const int wave = tid >> 6;
    const int lane = tid & 63;
    const int grp  = lane >> 4;
    const int sub  = lane & 15;
    const int j    = blockIdx.x % S_DIM;
    const int bloc = blockIdx.x / S_DIM;

    for (int chunk = 0; chunk < B_DIM / CB; ++chunk) {
        const int    b       = chunk * CB + bloc;
        const size_t base_bj = (size_t)b * SS;

        halfx4 st[NPASS][3];
        #pragma unroll
        for (int p = 0; p < NPASS; ++p) {
            const int i = p * 16 + wave * 4 + grp;
            const floatx4* rowp = reinterpret_cast<const floatx4*>(
                s_bin + (base_bj + (size_t)i * S_DIM + j) * S_DIM);
            #pragma unroll
            for (int c = 0; c < 3; ++c) {
                const int f4 = sub + (c << 4);
                floatx4 sv = __builtin_nontemporal_load(rowp + f4);
                const int k0 = f4 << 2;
                halfx4 hv;
                hv.x = (_Float16)((k0 + 0 != i && k0 + 0 != j) ? sv.x : 0.0f);
                hv.y = (_Float16)((k0 + 1 != i && k0 + 1 != j) ? sv.y : 0.0f);
                hv.z = (_Float16)((k0 + 2 != i && k0 + 2 != j) ? sv.z : 0.0f);
                hv.w = (_Float16)((k0 + 3 != i && k0 + 3 != j) ? sv.w : 0.0f);
                st[p][c] = hv;
            }
        }

        for (int it = 0; it < 3; ++it) {
            const float* src = (it == 0) ? s_con + base_bj + (size_t)j * S_DIM
                             : (it == 1) ? sigA  + base_bj + (size_t)j * S_DIM
                                         : sigB  + base_bj + (size_t)j * S_DIM;
            if (tid < S_DIM) {
                float v = src[tid];
                sig_row[tid] = (it == 0) ? sigmoidf(v) : v;
            }
            __syncthreads();

            float* dst = (it == 0) ? sigA : (it == 1) ? sigB : out;
            #pragma unroll
            for (int p = 0; p < NPASS; ++p) {
                const int i = p * 16 + wave * 4 + grp;
                float dot = 0.0f;
                #pragma unroll
                for (int c = 0; c < 3; ++c) {
                    const int f4 = sub + (c << 4);
                    halfx4 hv = st[p][c];
                    const float4 gv = *reinterpret_cast<const float4*>(&sig_row[f4 << 2]);
                    dot += (float)hv.x * gv.x + (float)hv.y * gv.y
                         + (float)hv.z * gv.z + (float)hv.w * gv.w;
                }
                dot += __shfl_xor(dot, 1, 64);
                dot += __shfl_xor(dot, 2, 64);
                dot += __shfl_xor(dot, 4, 64);
                dot += __shfl_xor(dot, 8, 64);
                if (sub == 0) {
                    const size_t row = base_bj + (size_t)i * S_DIM + j;
                    float q = s_con[row] + (mask[row] ? dot : 0.0f);
                    dst[row] = sigmoidf(q);
                }
            }
            __syncthreads();
            if (it < 2) grid.sync();
        }
    }
}

// ---------------- fallback path (proven R6, 104 us) ----------------
__global__ __launch_bounds__(256) void fb_first_kernel(const float* __restrict__ s_con,
                                                       const float* __restrict__ s_bin,
                                                       const int* __restrict__ mask,
                                                       half4s* __restrict__ sbh,
                                                       float* __restrict__ sig_out) {
    const int wave = threadIdx.x >> 6;
    const int lane = threadIdx.x & 63;
    const int grp  = lane >> 4;
    const int sub  = lane & 15;
    const int row  = (blockIdx.x * 4 + wave) * 4 + grp;

    const int b   = row / SS;
    const int rem = row - b * SS;
    const int i   = rem / S_DIM;
    const int j   = rem - i * S_DIM;

    const floatx4* __restrict__ srow = reinterpret_cast<const floatx4*>(s_bin + (size_t)row * S_DIM);
    const float4*  __restrict__ grow = reinterpret_cast<const float4*>(s_con + (size_t)(b * SS + j * S_DIM));
    half4s* __restrict__ hrow = sbh + (size_t)row * (S_DIM / 4);

    float dot = 0.0f;
    #pragma unroll
    for (int c = 0; c < 3; ++c) {
        const int f4 = sub + (c << 4);
        floatx4 sv = __builtin_nontemporal_load(srow + f4);
        float4  gv = grow[f4];
        const int k0 = f4 << 2;
        const float m0 = (k0 + 0 != i && k0 + 0 != j) ? sv.x : 0.0f;
        const float m1 = (k0 + 1 != i && k0 + 1 != j) ? sv.y : 0.0f;
        const float m2 = (k0 + 2 != i && k0 + 2 != j) ? sv.z : 0.0f;
        const float m3 = (k0 + 3 != i && k0 + 3 != j) ? sv.w : 0.0f;
        dot += m0 * sigmoidf(gv.x) + m1 * sigmoidf(gv.y)
             + m2 * sigmoidf(gv.z) + m3 * sigmoidf(gv.w);
        half4s hv;
        hv.x = (_Float16)m0; hv.y = (_Float16)m1;
        hv.z = (_Float16)m2; hv.w = (_Float16)m3;
        hrow[f4] = hv;
    }

    dot += __shfl_xor(dot, 1, 64);
    dot += __shfl_xor(dot, 2, 64);
    dot += __shfl_xor(dot, 4, 64);
    dot += __shfl_xor(dot, 8, 64);

    if (sub == 0) {
        float q = s_con[row] + (mask[row] ? dot : 0.0f);
        sig_out[row] = sigmoidf(q);
    }
}

__global__ __launch_bounds__(256) void fb_iter_kernel(const float* __restrict__ s_con,
                                                      const half4s* __restrict__ sbh,
                                                      const int* __restrict__ mask,
                                                      const float* __restrict__ sig_in,
                                                      float* __restrict__ sig_out) {
    const int wave = threadIdx.x >> 6;
    const int lane = threadIdx.x & 63;
    const int grp  = lane >> 4;
    const int sub  = lane & 15;
    const int row  = (blockIdx.x * 4 + wave) * 4 + grp;

    const int b   = row / SS;
    const int rem = row - b * SS;
    const int j   = rem - (rem / S_DIM) * S_DIM;

    const half4s* __restrict__ hrow = sbh + (size_t)row * (S_DIM / 4);
    const float4* __restrict__ grow = reinterpret_cast<const float4*>(sig_in + (size_t)(b * SS + j * S_DIM));

    float dot = 0.0f;
    #pragma unroll
    for (int c = 0; c < 3; ++c) {
        const int f4 = sub + (c << 4);
        half4s hv = hrow[f4];
        float4 gv = grow[f4];
        dot += (float)hv.x * gv.x + (float)hv.y * gv.y
             + (float)hv.z * gv.z + (float)hv.w * gv.w;
    }

    dot += __shfl_xor(dot, 1, 64);
    dot += __shfl_xor(dot, 2, 64);
    dot += __shfl_xor(dot, 4, 64);
    dot += __shfl_xor(dot, 8, 64);

    if (sub == 0) {
        float q = s_con[row] + (mask[row] ? dot : 0.0f);
        sig_out[row] = sigmoidf(q);
    }
}

extern "C" void kernel_launch(void* const* d_in, const int* in_sizes, int n_in,
                              void* d_out, int out_size, void* d_ws, size_t ws_size,
                              hipStream_t stream) {
    const float* s_con = (const float*)d_in[0];
    const float* s_bin = (const float*)d_in[1];
    const int*   mask  = (const int*)d_in[2];   // harness widens bool -> int32
    float* out  = (float*)d_out;
    float* sigA = (float*)d_ws;
    float* sigB = sigA + NROWS;
    half4s* sbh = reinterpret_cast<half4s*>(sigB + NROWS);  // fallback's fp16 copy

    void* args[] = { (void*)&s_con, (void*)&s_bin, (void*)&mask,
                     (void*)&sigA, (void*)&sigB, (void*)&out };

    // Tier 1: CB=4 (768 blocks, needs 3 blocks/CU, 4 grid syncs)
    int nb = 0;
    if (hipOccupancyMaxActiveBlocksPerMultiprocessor(&nb, fvi_coop_kernel<4>, 256, 0) == hipSuccess
        && nb >= 3) {
        if (hipLaunchCooperativeKernel((const void*)fvi_coop_kernel<4>,
                                       dim3(4 * S_DIM), dim3(256), args, 0, stream) == hipSuccess)
            return;
    }
    // Tier 2: CB=2 (384 blocks, needs 2 blocks/CU, 8 grid syncs)
    nb = 0;
    if (hipOccupancyMaxActiveBlocksPerMultiprocessor(&nb, fvi_coop_kernel<2>, 256, 0) == hipSuccess
        && nb >= 2) {
        if (hipLaunchCooperativeKernel((const void*)fvi_coop_kernel<2>,
                                       dim3(2 * S_DIM), dim3(256), args, 0, stream) == hipSuccess)
            return;
    }
    // Tier 3: proven 3-dispatch path
    const dim3 grid(NROWS / 16);
    fb_first_kernel<<<grid, 256, 0, stream>>>(s_con, s_bin, mask, sbh, sigA);
    fb_iter_kernel <<<grid, 256, 0, stream>>>(s_con, sbh, mask, sigA, sigB);
    fb_iter_kernel <<<grid, 256, 0, stream>>>(s_con, sbh, mask, sigB, out);
}